// Round 11
// baseline (623.476 us; speedup 1.0000x reference)
//
#include <hip/hip_runtime.h>
#include <cstdint>
#include <cstddef>

#define TT 2048
#define CC 768
#define KK 5

typedef __attribute__((ext_vector_type(8))) short short8;
typedef __attribute__((ext_vector_type(4))) short short4v;
typedef __attribute__((ext_vector_type(4))) float float4v;

struct PairTab { int sa[12]; int sb[12]; };

#define N_SELF_BLK (8 * 136)   // 8 slices x 136 upper-triangle 128x128 tiles
#define N_CROSS_BLK (12 * 256) // 12 pairs x 256 tiles
#define TP 132                 // padded LDS tile row (ushorts): 2-way banks, 8B-aligned rows

// ---------------- device RNG hash ----------------
__device__ __forceinline__ unsigned int mix_hash(unsigned int a, unsigned int b) {
  unsigned long long x = (((unsigned long long)a) << 32) | (unsigned long long)b;
  x ^= x >> 33; x *= 0xff51afd7ed558ccdULL;
  x ^= x >> 33; x *= 0xc4ceb9fe1a85ec53ULL;
  x ^= x >> 33;
  return (unsigned int)(x & 0xffffffffu);
}

__device__ __forceinline__ unsigned short f2bf(float x) {  // RNE fp32->bf16
  union { float f; unsigned int u; } v; v.f = x;
  unsigned int r = v.u + 0x7fffu + ((v.u >> 16) & 1u);
  return (unsigned short)(r >> 16);
}

__device__ __forceinline__ float bf2f(unsigned short u) {
  union { unsigned int i; float f; } v; v.i = ((unsigned int)u) << 16; return v.f;
}

__device__ __forceinline__ void gload_lds16(const void* g, void* l) {
  __builtin_amdgcn_global_load_lds(
      (const __attribute__((address_space(1))) unsigned int*)g,
      (__attribute__((address_space(3))) unsigned int*)l, 16, 0, 0);
}

__device__ __forceinline__ bool lexlt(float k1, int i1, float k2, int i2) {
  return k1 < k2 || (k1 == k2 && i1 < i2);
}

#define INS5(kk_, ii_, L)                                                        \
  if (lexlt(kk_, ii_, L##k[4], L##i[4])) {                                       \
    L##k[4] = kk_; L##i[4] = ii_;                                                \
    if (lexlt(L##k[4], L##i[4], L##k[3], L##i[3])) {                             \
      float tk = L##k[3]; int ti_ = L##i[3]; L##k[3] = L##k[4]; L##i[3] = L##i[4]; L##k[4] = tk; L##i[4] = ti_; \
      if (lexlt(L##k[3], L##i[3], L##k[2], L##i[2])) {                           \
        tk = L##k[2]; ti_ = L##i[2]; L##k[2] = L##k[3]; L##i[2] = L##i[3]; L##k[3] = tk; L##i[3] = ti_; \
        if (lexlt(L##k[2], L##i[2], L##k[1], L##i[1])) {                         \
          tk = L##k[1]; ti_ = L##i[1]; L##k[1] = L##k[2]; L##i[1] = L##i[2]; L##k[2] = tk; L##i[2] = ti_; \
          if (lexlt(L##k[1], L##i[1], L##k[0], L##i[0])) {                       \
            tk = L##k[0]; ti_ = L##i[0]; L##k[0] = L##k[1]; L##i[0] = L##i[1]; L##k[1] = tk; L##i[1] = ti_; \
          }                                                                      \
        }                                                                        \
      }                                                                          \
    }                                                                            \
  }

// ---------------- fused prep: fp32->bf16 + row sumsq/inv-norm ----------------
__global__ __launch_bounds__(192) void prep_kernel(const float* __restrict__ z1, const float* __restrict__ z2,
                                                   unsigned short* __restrict__ zb, float* __restrict__ sq,
                                                   float* __restrict__ inv) {
  int r = blockIdx.x;  // 0..16383
  const float* p = (r < 4 * TT) ? (z1 + (size_t)r * CC) : (z2 + (size_t)(r - 4 * TT) * CC);
  unsigned short* o = zb + (size_t)r * CC;
  float4 v = ((const float4*)p)[threadIdx.x];
  float s = v.x * v.x + v.y * v.y + v.z * v.z + v.w * v.w;
  ushort4 u;
  u.x = f2bf(v.x); u.y = f2bf(v.y); u.z = f2bf(v.z); u.w = f2bf(v.w);
  ((ushort4*)o)[threadIdx.x] = u;
#pragma unroll
  for (int off = 32; off > 0; off >>= 1) s += __shfl_down(s, off, 64);
  __shared__ float wred[3];
  int lane = threadIdx.x & 63, w = threadIdx.x >> 6;
  if (lane == 0) wred[w] = s;
  __syncthreads();
  if (threadIdx.x == 0) {
    float tot = wred[0] + wred[1] + wred[2];
    sq[r] = tot; inv[r] = rsqrtf(tot + 1e-12f);
  }
}

// ---------------- unified gram kernel: BK=64, XOR-swizzled LDS; bf16 gram via LDS-staged epilogue ----------------
__global__ __launch_bounds__(256) void gram_all(const unsigned short* __restrict__ zb, unsigned short* __restrict__ gram,
                                                const float* __restrict__ invAll, PairTab tab,
                                                float* __restrict__ prow_v, int* __restrict__ prow_i,
                                                float* __restrict__ pcol_v, int* __restrict__ pcol_i) {
  __shared__ union {
    struct { unsigned short As[128 * 64]; unsigned short Bs[128 * 64]; } st;   // 32768 B (K-loop)
    unsigned short tile[128 * TP];                                             // 33792 B (self epilogue)
  } sm;
  __shared__ float sInvA[128], sInvB[128];
  __shared__ float rowv[2][128]; __shared__ int rowi[2][128];
  __shared__ float colv[2][128]; __shared__ int coli[2][128];

  const int bid = blockIdx.x;
  const bool isSelf = bid < N_SELF_BLK;
  int bm, bn, p = 0, s = 0;
  const unsigned short *A, *B;
  if (isSelf) {
    s = bid / 136;
    int t = bid % 136;
    int ti = 0;
    while (t >= 16 - ti) { t -= 16 - ti; ++ti; }
    int tj = ti + t;           // ti <= tj
    bm = ti * 128; bn = tj * 128;
    A = zb + (size_t)s * TT * CC;
    B = A;
  } else {
    int cb = bid - N_SELF_BLK;
    p = cb >> 8;
    int tile = cb & 255;
    bn = (tile & 15) * 128;
    bm = (tile >> 4) * 128;
    A = zb + (size_t)tab.sa[p] * TT * CC;
    B = zb + (size_t)tab.sb[p] * TT * CC;
    const float* invA = invAll + (size_t)tab.sa[p] * TT;
    const float* invB = invAll + (size_t)tab.sb[p] * TT;
    if (threadIdx.x < 128) sInvA[threadIdx.x] = invA[bm + threadIdx.x];
    else sInvB[threadIdx.x - 128] = invB[bn + threadIdx.x - 128];
  }
  const int lane = threadIdx.x & 63, waveId = threadIdx.x >> 6;
  const int wm = (waveId >> 1) * 64, wn = (waveId & 1) * 64;
  const int lrow = lane & 15, lquad = lane >> 4;

  float4v acc[4][4];
#pragma unroll
  for (int i = 0; i < 4; ++i)
#pragma unroll
    for (int j = 0; j < 4; ++j) acc[i][j] = (float4v){0.f, 0.f, 0.f, 0.f};

  for (int kk = 0; kk < CC; kk += 64) {
    // stage 128x64 per matrix; LDS slot l holds global chunk (l&7)^(row&7) -> swizzled (conflict-free)
#pragma unroll
    for (int c = 0; c < 4; ++c) {
      int l = c * 256 + threadIdx.x;        // 0..1023 chunks of 8 shorts
      int row = l >> 3, pc = l & 7;
      int sc = pc ^ (row & 7);
      gload_lds16(A + (size_t)(bm + row) * CC + kk + sc * 8, &sm.st.As[l * 8]);
      gload_lds16(B + (size_t)(bn + row) * CC + kk + sc * 8, &sm.st.Bs[l * 8]);
    }
    __syncthreads();
#pragma unroll
    for (int h = 0; h < 2; ++h) {
      short8 af[4], bfr[4];
#pragma unroll
      for (int i = 0; i < 4; ++i) {
        int ra = wm + i * 16 + lrow;
        int ca = (h * 4 + lquad) ^ (ra & 7);
        af[i] = *(const short8*)&sm.st.As[ra * 64 + ca * 8];
        int rb = wn + i * 16 + lrow;
        int cb2 = (h * 4 + lquad) ^ (rb & 7);
        bfr[i] = *(const short8*)&sm.st.Bs[rb * 64 + cb2 * 8];
      }
#pragma unroll
      for (int i = 0; i < 4; ++i)
#pragma unroll
        for (int j = 0; j < 4; ++j)
          acc[i][j] = __builtin_amdgcn_mfma_f32_16x16x32_bf16(af[i], bfr[j], acc[i][j], 0, 0, 0);
    }
    __syncthreads();
  }

  if (isSelf) {
    // ---- scatter acc -> LDS tile as bf16 (2-way banks with TP=132, free) ----
#pragma unroll
    for (int i = 0; i < 4; ++i)
#pragma unroll
      for (int j = 0; j < 4; ++j)
#pragma unroll
        for (int r = 0; r < 4; ++r) {
          int lr = wm + i * 16 + lquad * 4 + r;
          int lc = wn + j * 16 + lrow;
          sm.tile[lr * TP + lc] = f2bf(acc[i][j][r]);
        }
    __syncthreads();
    unsigned short* G = gram + (size_t)s * TT * TT;
    // ---- direct rows: coalesced 8B stores from LDS ----
    for (int it = 0; it < 16; ++it) {
      int task = it * 256 + threadIdx.x;
      int r = task >> 5;          // 0..127
      int c = task & 31;          // chunk of 4 ushorts
      short4v v = *(const short4v*)&sm.tile[r * TP + c * 4];
      *(short4v*)&G[(size_t)(bm + r) * TT + bn + c * 4] = v;
    }
    // ---- mirror rows (offdiag): transposed LDS reads, coalesced 8B stores ----
    if (bm != bn) {
      for (int it = 0; it < 16; ++it) {
        int task = it * 256 + threadIdx.x;
        int cc = task >> 5;       // mirror row = original col 0..127
        int q = task & 31;        // chunk of 4 original rows
        short4v v;
        v[0] = (short)sm.tile[(q * 4 + 0) * TP + cc];
        v[1] = (short)sm.tile[(q * 4 + 1) * TP + cc];
        v[2] = (short)sm.tile[(q * 4 + 2) * TP + cc];
        v[3] = (short)sm.tile[(q * 4 + 3) * TP + cc];
        *(short4v*)&G[(size_t)(bn + cc) * TT + bm + q * 4] = v;
      }
    }
    return;
  }

  // ---- cross: fused dual argmin partials (fp32 acc, unchanged) ----
  float rbv[4][4]; int rbi[4][4];
#pragma unroll
  for (int i = 0; i < 4; ++i)
#pragma unroll
    for (int r = 0; r < 4; ++r) { rbv[i][r] = INFINITY; rbi[i][r] = TT; }
#pragma unroll
  for (int i = 0; i < 4; ++i)
#pragma unroll
    for (int j = 0; j < 4; ++j) {
      int col = bn + wn + j * 16 + lrow;
      float ivb = sInvB[wn + j * 16 + lrow];
#pragma unroll
      for (int r = 0; r < 4; ++r) {
        float v = -acc[i][j][r] * ivb;
        if (v < rbv[i][r]) { rbv[i][r] = v; rbi[i][r] = col; }
      }
    }
#pragma unroll
  for (int m = 1; m <= 8; m <<= 1) {
#pragma unroll
    for (int i = 0; i < 4; ++i)
#pragma unroll
      for (int r = 0; r < 4; ++r) {
        float v2 = __shfl_xor(rbv[i][r], m, 64);
        int i2 = __shfl_xor(rbi[i][r], m, 64);
        if (v2 < rbv[i][r] || (v2 == rbv[i][r] && i2 < rbi[i][r])) { rbv[i][r] = v2; rbi[i][r] = i2; }
      }
  }
  if (lrow == 0) {
#pragma unroll
    for (int i = 0; i < 4; ++i)
#pragma unroll
      for (int r = 0; r < 4; ++r) {
        int lr = wm + i * 16 + lquad * 4 + r;
        rowv[wn >> 6][lr] = rbv[i][r]; rowi[wn >> 6][lr] = rbi[i][r];
      }
  }

  float cbv[4]; int cbi[4];
#pragma unroll
  for (int j = 0; j < 4; ++j) { cbv[j] = INFINITY; cbi[j] = TT; }
#pragma unroll
  for (int j = 0; j < 4; ++j)
#pragma unroll
    for (int i = 0; i < 4; ++i)
#pragma unroll
      for (int r = 0; r < 4; ++r) {
        int lr = wm + i * 16 + lquad * 4 + r;
        float v = -acc[i][j][r] * sInvA[lr];
        if (v < cbv[j]) { cbv[j] = v; cbi[j] = bm + lr; }
      }
#pragma unroll
  for (int m = 16; m <= 32; m <<= 1) {
#pragma unroll
    for (int j = 0; j < 4; ++j) {
      float v2 = __shfl_xor(cbv[j], m, 64);
      int i2 = __shfl_xor(cbi[j], m, 64);
      if (v2 < cbv[j] || (v2 == cbv[j] && i2 < cbi[j])) { cbv[j] = v2; cbi[j] = i2; }
    }
  }
  if (lquad == 0) {
#pragma unroll
    for (int j = 0; j < 4; ++j) {
      int lc = wn + j * 16 + lrow;
      colv[wm >> 6][lc] = cbv[j]; coli[wm >> 6][lc] = cbi[j];
    }
  }
  __syncthreads();

  int bj = bn >> 7, bi2 = bm >> 7;
  if (threadIdx.x < 128) {
    int t = threadIdx.x;
    float v0 = rowv[0][t], v1 = rowv[1][t];
    int i0 = rowi[0][t], i1 = rowi[1][t];
    bool take1 = (v1 < v0) || (v1 == v0 && i1 < i0);
    prow_v[((size_t)p * 16 + bj) * TT + bm + t] = take1 ? v1 : v0;
    prow_i[((size_t)p * 16 + bj) * TT + bm + t] = take1 ? i1 : i0;
  } else {
    int t = threadIdx.x - 128;
    float v0 = colv[0][t], v1 = colv[1][t];
    int i0 = coli[0][t], i1 = coli[1][t];
    bool take1 = (v1 < v0) || (v1 == v0 && i1 < i0);
    pcol_v[((size_t)p * 16 + bi2) * TT + bn + t] = take1 ? v1 : v0;
    pcol_i[((size_t)p * 16 + bi2) * TT + bn + t] = take1 ? i1 : i0;
  }
}

// ---------------- argmin stage 2 ----------------
__global__ __launch_bounds__(256) void argmin_reduce_batched(const float* __restrict__ prow_v, const int* __restrict__ prow_i,
                                                             const float* __restrict__ pcol_v, const int* __restrict__ pcol_i,
                                                             int* __restrict__ b_of_a, int* __restrict__ a_of_b) {
  int p = blockIdx.y;
  int t = blockIdx.x * 256 + threadIdx.x;
  int isRow = t < TT;
  int x = isRow ? t : t - TT;
  const float* pv = (isRow ? prow_v : pcol_v) + (size_t)p * 16 * TT;
  const int* pi = (isRow ? prow_i : pcol_i) + (size_t)p * 16 * TT;
  float best = INFINITY; int bidx = TT;
  for (int s = 0; s < 16; ++s) {
    float v = pv[(size_t)s * TT + x]; int id = pi[(size_t)s * TT + x];
    if (v < best || (v == best && id < bidx)) { best = v; bidx = id; }
  }
  if (isRow) b_of_a[(size_t)p * TT + x] = bidx;
  else       a_of_b[(size_t)p * TT + x] = bidx;
}

// ---------------- single-pass dual top-5: one wave per row (bf16 gram) ----------------
__global__ __launch_bounds__(256) void top5_batched(const unsigned short* __restrict__ gram, const float* __restrict__ sqAll,
                                                    const float* __restrict__ invAll, int* __restrict__ out0,
                                                    int* __restrict__ out1) {
  int s = blockIdx.y;
  int w = threadIdx.x >> 6, lane = threadIdx.x & 63;
  int i = blockIdx.x * 4 + w;
  const unsigned short* G = gram + (size_t)s * TT * TT + (size_t)i * TT;
  const float* sq = sqAll + (size_t)s * TT;
  const float* inv = invAll + (size_t)s * TT;

  float ak[5]; int ai[5];   // mode0 (sq-dist)
  float bk[5]; int bi[5];   // mode1 (cos-dist)
#pragma unroll
  for (int t = 0; t < 5; ++t) { ak[t] = INFINITY; ai[t] = TT; bk[t] = INFINITY; bi[t] = TT; }

#pragma unroll
  for (int step = 0; step < 8; ++step) {
    int j4 = (step * 64 + lane) * 4;
    ushort4 g4u = *(const ushort4*)&G[j4];
    float4 s4 = *(const float4*)&sq[j4];
    float4 v4 = *(const float4*)&inv[j4];
#pragma unroll
    for (int c = 0; c < 4; ++c) {
      int j = j4 + c;
      float g = bf2f((c == 0) ? g4u.x : (c == 1) ? g4u.y : (c == 2) ? g4u.z : g4u.w);
      float sv = (c == 0) ? s4.x : (c == 1) ? s4.y : (c == 2) ? s4.z : s4.w;
      float iv = (c == 0) ? v4.x : (c == 1) ? v4.y : (c == 2) ? v4.z : v4.w;
      float k0 = (j == i) ? INFINITY : sv - 2.f * g;
      float k1 = (j == i) ? INFINITY : -g * iv;
      INS5(k0, j, a)
      INS5(k1, j, b)
    }
  }
  // butterfly merge across 64 lanes
#pragma unroll
  for (int m = 1; m <= 32; m <<= 1) {
    float ok[5]; int oi[5];
#pragma unroll
    for (int t = 0; t < 5; ++t) { ok[t] = __shfl_xor(ak[t], m, 64); oi[t] = __shfl_xor(ai[t], m, 64); }
#pragma unroll
    for (int t = 0; t < 5; ++t) { INS5(ok[t], oi[t], a) }
#pragma unroll
    for (int t = 0; t < 5; ++t) { ok[t] = __shfl_xor(bk[t], m, 64); oi[t] = __shfl_xor(bi[t], m, 64); }
#pragma unroll
    for (int t = 0; t < 5; ++t) { INS5(ok[t], oi[t], b) }
  }
  if (lane < KK) {
    int v0 = (lane == 0) ? ai[0] : (lane == 1) ? ai[1] : (lane == 2) ? ai[2] : (lane == 3) ? ai[3] : ai[4];
    int v1 = (lane == 0) ? bi[0] : (lane == 1) ? bi[1] : (lane == 2) ? bi[2] : (lane == 3) ? bi[3] : bi[4];
    out0[((size_t)s * TT + i) * KK + lane] = v0;
    out1[((size_t)s * TT + i) * KK + lane] = v1;
  }
}

// ---------------- mutual matching, batched ----------------
__global__ __launch_bounds__(256) void mutual_batched(const int* __restrict__ b_of_a_all,
                                                      const int* __restrict__ a_of_b_all,
                                                      int* __restrict__ idxB_all, int* __restrict__ matchedB_all,
                                                      int* __restrict__ unmatched_all, int* __restrict__ scalars_all) {
  int p = blockIdx.x;
  const int* b_of_a = b_of_a_all + (size_t)p * TT;
  const int* a_of_b = a_of_b_all + (size_t)p * TT;
  int* idxB_of_A = idxB_all + (size_t)p * TT;
  int* matchedB = matchedB_all + (size_t)p * TT;
  int* unmatched = unmatched_all + (size_t)p * TT;
  __shared__ int cnt_sh;
  for (int j = threadIdx.x; j < TT; j += 256) matchedB[j] = 0;
  __syncthreads();
  for (int i = threadIdx.x; i < TT; i += 256) {
    int b = b_of_a[i];
    bool mut = (a_of_b[b] == i);
    idxB_of_A[i] = mut ? b : -1;
    if (mut) matchedB[b] = 1;
  }
  __syncthreads();
  if (threadIdx.x == 0) cnt_sh = 0;
  __syncthreads();
  for (int j = threadIdx.x; j < TT; j += 256) {
    if (!matchedB[j]) { int q = atomicAdd(&cnt_sh, 1); unmatched[q] = j; }
  }
  __syncthreads();
  if (threadIdx.x == 0) {
    int c = cnt_sh;
    if (c == 0) { unmatched[0] = 0; c = 1; }
    scalars_all[p * 16] = c;
  }
}

// ---------------- crossbrain hinge: 64 rows/block, 1 atomic/block ----------------
__global__ __launch_bounds__(256) void cb_hinge_block(const unsigned short* __restrict__ gram, const float* __restrict__ invAll,
                                                      const int* __restrict__ neigh1, float* __restrict__ cb_acc) {
  int c = blockIdx.y;
  int i0 = blockIdx.x * 64;
  int sa = c, sb = (c < 4) ? (c + 4) : (c - 4);
  const unsigned short* Gs = gram + (size_t)sb * TT * TT;
  const float* invB = invAll + (size_t)sb * TT;
  const int* neighA = neigh1 + (size_t)sa * TT * KK;
  unsigned int seed = 0x13579BDFu + 0x9E3779B9u * (unsigned)c;
  int tid = threadIdx.x;

  __shared__ int targ[64][10];
  __shared__ float sval[64][10];
  for (int t = tid; t < 64 * KK; t += 256) targ[t / KK][t % KK] = neighA[(size_t)i0 * KK + t];
  __syncthreads();
  if (tid < 64) {
    int i = i0 + tid;
    int pos[KK];
#pragma unroll
    for (int k = 0; k < KK; ++k) pos[k] = targ[tid][k];
    unsigned int ctr = 0;
    for (int k = 0; k < KK; ++k) {
      int cand;
      while (true) {
        unsigned int h = mix_hash(seed ^ (unsigned)i, ctr++);
        cand = (int)(h & (TT - 1));
        bool bad = (cand == i);
        for (int t = 0; t < KK; ++t) bad = bad || (cand == pos[t]);
        for (int t = 0; t < k; ++t) bad = bad || (cand == targ[tid][KK + t]);
        if (!bad) break;
      }
      targ[tid][KK + k] = cand;
    }
  }
  __syncthreads();
  for (int t = tid; t < 640; t += 256) {
    int il = t / 10, k = t % 10;
    int tt = targ[il][k];
    sval[il][k] = bf2f(Gs[(size_t)(i0 + il) * TT + tt]) * invB[tt];
  }
  __syncthreads();
  if (tid < 64) {
    int i = i0 + tid;
    float ii = invB[i];
    const float lo = -1.f + 1e-8f, hi = 1.f - 1e-8f;
    float hsum = 0.f;
#pragma unroll
    for (int k = 0; k < KK; ++k) {
      float sp = fminf(fmaxf(sval[tid][k] * ii, lo), hi);
      float sn = fminf(fmaxf(sval[tid][KK + k] * ii, lo), hi);
      float h = sn - sp + 0.05f;
      hsum += (h > 0.f) ? h : 0.f;
    }
#pragma unroll
    for (int off = 32; off > 0; off >>= 1) hsum += __shfl_down(hsum, off, 64);
    if (tid == 0) atomicAdd(&cb_acc[c], hsum);
  }
}

// ---------------- NRC hinge: 64 rows/block, 2 atomics/block ----------------
__global__ __launch_bounds__(256) void nrc_hinge_block(const unsigned short* __restrict__ gram, const float* __restrict__ invAll,
                                                       const int* __restrict__ neighC, const int* __restrict__ idxB_all,
                                                       const int* __restrict__ unmatched_all,
                                                       const int* __restrict__ scalars_all,
                                                       PairTab tab, float* __restrict__ nrc_acc) {
  int p = blockIdx.y;
  int i0 = blockIdx.x * 64;
  int sa = tab.sa[p], sb = tab.sb[p];
  const unsigned short* Gs = gram + (size_t)sb * TT * TT;
  const float* invB = invAll + (size_t)sb * TT;
  const int* neighA = neighC + (size_t)sa * TT * KK;
  const int* idxB_of_A = idxB_all + (size_t)p * TT;
  const int* unmatched = unmatched_all + (size_t)p * TT;
  unsigned int seed = 0xC0FFEE11u + 0x9E3779B9u * (unsigned)p;
  float* acc = nrc_acc + p * 2;
  int tid = threadIdx.x;

  __shared__ int targ[64][10];
  __shared__ float sval[64][10];
  __shared__ unsigned int tmask[64];
  __shared__ int su[64];
  if (tid < 64) { tmask[tid] = 0; su[tid] = idxB_of_A[i0 + tid]; }
  __syncthreads();
  unsigned int neg_count = (unsigned int)scalars_all[p * 16];
  for (int t = tid; t < 64 * KK; t += 256) {
    int il = t / KK, k = t % KK;
    int nb = neighA[(size_t)i0 * KK + t];
    int pb = idxB_of_A[nb];
    targ[il][k] = (pb >= 0) ? pb : 0;
    if (pb >= 0) atomicOr(&tmask[il], 1u << k);
  }
  for (int t = tid; t < 64 * KK; t += 256) {
    int il = t / KK, k = t % KK;
    int i = i0 + il;
    unsigned int r = mix_hash(seed ^ 0xA5A5u, (unsigned)(i * KK + k)) & (TT - 1);
    targ[il][KK + k] = unmatched[r % neg_count];
  }
  __syncthreads();
  for (int t = tid; t < 640; t += 256) {
    int il = t / 10, k = t % 10;
    int u = su[il] >= 0 ? su[il] : 0;
    int tt = targ[il][k];
    sval[il][k] = bf2f(Gs[(size_t)u * TT + tt]) * invB[tt];
  }
  __syncthreads();
  if (tid < 64) {
    int idx = su[tid];
    int u = idx >= 0 ? idx : 0;
    float iu = invB[u];
    unsigned int tm = tmask[tid];
    float hsum = 0.f; int pcnt = 0;
#pragma unroll
    for (int k = 0; k < KK; ++k) {
      if (tm & (1u << k)) {
        float dpos = 1.f - sval[tid][k] * iu;
        float dneg = 1.f - sval[tid][KK + k] * iu;
        float h = dpos - dneg + 0.4f;
        hsum += (h > 0.f) ? h : 0.f;
        pcnt++;
      }
    }
    float hs = 0.f, vc = 0.f;
    if (idx >= 0 && pcnt > 0) { hs = hsum / (float)pcnt; vc = 1.0f; }
#pragma unroll
    for (int off = 32; off > 0; off >>= 1) {
      hs += __shfl_down(hs, off, 64);
      vc += __shfl_down(vc, off, 64);
    }
    if (tid == 0) {
      atomicAdd(&acc[0], hs);
      atomicAdd(&acc[1], vc);
    }
  }
}

// ---------------- final combine ----------------
__global__ void final_kernel(const float* __restrict__ cb_acc, const float* __restrict__ nrc_acc,
                             float* __restrict__ out) {
  float loss2 = 0.f;
  for (int c = 0; c < 8; ++c) loss2 += cb_acc[c] * (1.0f / 10240.0f);
  loss2 *= 0.25f;
  float loss3 = 0.f;
  for (int d = 0; d < 2; ++d) {
    float s = 0.f;
    for (int t = 0; t < 6; ++t) {
      float cnt = nrc_acc[(d * 6 + t) * 2 + 1];
      float sum = nrc_acc[(d * 6 + t) * 2 + 0];
      s += (cnt > 0.f) ? (sum / cnt) : 0.f;
    }
    loss3 += s * (1.f / 6.f);
  }
  out[0] = 10.f * loss2 + 10.f * loss3;
}

// ---------------- host-side numpy RandomState(seed).permutation(12)[:6] ----------------
namespace {
struct MT19937 {
  uint32_t mt[624]; int mti;
  void seed(uint32_t s) {
    mt[0] = s;
    for (int i = 1; i < 624; ++i) mt[i] = 1812433253u * (mt[i - 1] ^ (mt[i - 1] >> 30)) + (uint32_t)i;
    mti = 624;
  }
  uint32_t next() {
    if (mti >= 624) {
      for (int i = 0; i < 624; ++i) {
        uint32_t y = (mt[i] & 0x80000000u) | (mt[(i + 1) % 624] & 0x7fffffffu);
        uint32_t v = y >> 1;
        if (y & 1u) v ^= 0x9908b0dfu;
        mt[i] = mt[(i + 397) % 624] ^ v;
      }
      mti = 0;
    }
    uint32_t y = mt[mti++];
    y ^= y >> 11; y ^= (y << 7) & 0x9d2c5680u; y ^= (y << 15) & 0xefc60000u; y ^= y >> 18;
    return y;
  }
  uint32_t interval(uint32_t mx) {
    uint32_t mask = mx;
    mask |= mask >> 1; mask |= mask >> 2; mask |= mask >> 4; mask |= mask >> 8; mask |= mask >> 16;
    while (true) { uint32_t v = next() & mask; if (v <= mx) return v; }
  }
};
inline void np_perm12_first6(uint32_t seed, int* sel6) {
  int a[12]; for (int i = 0; i < 12; ++i) a[i] = i;
  MT19937 r; r.seed(seed);
  for (int i = 11; i >= 1; --i) { uint32_t j = r.interval((uint32_t)i); int t = a[i]; a[i] = a[j]; a[j] = t; }
  for (int i = 0; i < 6; ++i) sel6[i] = a[i];
}
}  // namespace

extern "C" void kernel_launch(void* const* d_in, const int* in_sizes, int n_in,
                              void* d_out, int out_size, void* d_ws, size_t ws_size,
                              hipStream_t stream) {
  const float* z1 = (const float*)d_in[0];
  const float* z2 = (const float*)d_in[1];
  float* out = (float*)d_out;

  char* base = (char*)d_ws;
  size_t off = 0;
  auto alloc = [&](size_t bytes) -> void* {
    void* p = base + off;
    off = (off + bytes + 255) & ~(size_t)255;
    return p;
  };
  unsigned short* gram   = (unsigned short*)alloc((size_t)8 * TT * TT * 2);  // 67 MB bf16 self grams
  unsigned short* zb     = (unsigned short*)alloc((size_t)8 * TT * CC * 2);
  float* sq              = (float*)alloc((size_t)8 * TT * 4);
  float* inv             = (float*)alloc((size_t)8 * TT * 4);
  int*   neigh1          = (int*)alloc((size_t)8 * TT * KK * 4);
  int*   neighC          = (int*)alloc((size_t)8 * TT * KK * 4);
  float* prow_v          = (float*)alloc((size_t)12 * 16 * TT * 4);
  int*   prow_i          = (int*)alloc((size_t)12 * 16 * TT * 4);
  float* pcol_v          = (float*)alloc((size_t)12 * 16 * TT * 4);
  int*   pcol_i          = (int*)alloc((size_t)12 * 16 * TT * 4);
  int*   b_of_a          = (int*)alloc((size_t)12 * TT * 4);
  int*   a_of_b          = (int*)alloc((size_t)12 * TT * 4);
  int*   idxB            = (int*)alloc((size_t)12 * TT * 4);
  int*   matchedB        = (int*)alloc((size_t)12 * TT * 4);
  int*   unmatched       = (int*)alloc((size_t)12 * TT * 4);
  int*   scalars         = (int*)alloc(12 * 16 * 4);
  float* accs            = (float*)alloc(64 * 4);
  float* cb_acc          = accs;
  float* nrc_acc         = accs + 8;

  hipMemsetAsync(accs, 0, 64 * 4, stream);

  // NRC pair selection (numpy RandomState(seed).permutation(12)[:6])
  int sel0[6], sel1[6];
  np_perm12_first6(0u, sel0);
  np_perm12_first6(1u, sel1);
  static const int PP[12] = {0, 0, 0, 1, 1, 1, 2, 2, 2, 3, 3, 3};
  static const int QQ[12] = {1, 2, 3, 0, 2, 3, 0, 1, 3, 0, 1, 2};
  PairTab tab;
  for (int d = 0; d < 2; ++d) {
    const int* sel = (d == 0) ? sel0 : sel1;
    for (int t = 0; t < 6; ++t) {
      int pi_ = PP[sel[t]], qi = QQ[sel[t]];
      int p = d * 6 + t;
      tab.sa[p] = (d == 0) ? pi_ : 4 + pi_;
      tab.sb[p] = (d == 0) ? 4 + qi : qi;
    }
  }

  // fused prep (bf16 convert + norms)
  prep_kernel<<<8 * TT, 192, 0, stream>>>(z1, z2, zb, sq, inv);

  // unified gram: self upper-triangle (bf16 store via LDS staging, mirror) + cross with fused argmin
  gram_all<<<N_SELF_BLK + N_CROSS_BLK, 256, 0, stream>>>(zb, gram, inv, tab, prow_v, prow_i, pcol_v, pcol_i);

  // self-dependent phase
  top5_batched<<<dim3(TT / 4, 8), 256, 0, stream>>>(gram, sq, inv, neigh1, neighC);
  cb_hinge_block<<<dim3(TT / 64, 8), 256, 0, stream>>>(gram, inv, neigh1, cb_acc);

  // cross-dependent phase
  argmin_reduce_batched<<<dim3(2 * TT / 256, 12), 256, 0, stream>>>(prow_v, prow_i, pcol_v, pcol_i, b_of_a, a_of_b);
  mutual_batched<<<12, 256, 0, stream>>>(b_of_a, a_of_b, idxB, matchedB, unmatched, scalars);
  nrc_hinge_block<<<dim3(TT / 64, 12), 256, 0, stream>>>(gram, inv, neighC, idxB, unmatched, scalars, tab, nrc_acc);

  final_kernel<<<1, 1, 0, stream>>>(cb_acc, nrc_acc, out);
}

// Round 12
// 368.347 us; speedup vs baseline: 1.6926x; 1.6926x over previous
//
#include <hip/hip_runtime.h>
#include <cstdint>
#include <cstddef>

#define TT 2048
#define CC 768
#define KK 5

typedef __attribute__((ext_vector_type(8))) short short8;
typedef __attribute__((ext_vector_type(4))) short short4v;
typedef __attribute__((ext_vector_type(4))) float float4v;

struct PairTab { int sa[12]; int sb[12]; };

#define N_SELF_BLK (8 * 136)   // 8 slices x 136 upper-triangle 128x128 tiles
#define N_CROSS_BLK (12 * 256) // 12 pairs x 256 tiles
#define TP 132                 // padded LDS tile row (ushorts)

// ---------------- device RNG hash ----------------
__device__ __forceinline__ unsigned int mix_hash(unsigned int a, unsigned int b) {
  unsigned long long x = (((unsigned long long)a) << 32) | (unsigned long long)b;
  x ^= x >> 33; x *= 0xff51afd7ed558ccdULL;
  x ^= x >> 33; x *= 0xc4ceb9fe1a85ec53ULL;
  x ^= x >> 33;
  return (unsigned int)(x & 0xffffffffu);
}

__device__ __forceinline__ unsigned short f2bf(float x) {  // RNE fp32->bf16
  union { float f; unsigned int u; } v; v.f = x;
  unsigned int r = v.u + 0x7fffu + ((v.u >> 16) & 1u);
  return (unsigned short)(r >> 16);
}

__device__ __forceinline__ float bf2f(unsigned short u) {
  union { unsigned int i; float f; } v; v.i = ((unsigned int)u) << 16; return v.f;
}

__device__ __forceinline__ void gload_lds16(const void* g, void* l) {
  __builtin_amdgcn_global_load_lds(
      (const __attribute__((address_space(1))) unsigned int*)g,
      (__attribute__((address_space(3))) unsigned int*)l, 16, 0, 0);
}

__device__ __forceinline__ bool lexlt(float k1, int i1, float k2, int i2) {
  return k1 < k2 || (k1 == k2 && i1 < i2);
}

#define INS5(kk_, ii_, L)                                                        \
  if (lexlt(kk_, ii_, L##k[4], L##i[4])) {                                       \
    L##k[4] = kk_; L##i[4] = ii_;                                                \
    if (lexlt(L##k[4], L##i[4], L##k[3], L##i[3])) {                             \
      float tk = L##k[3]; int ti_ = L##i[3]; L##k[3] = L##k[4]; L##i[3] = L##i[4]; L##k[4] = tk; L##i[4] = ti_; \
      if (lexlt(L##k[3], L##i[3], L##k[2], L##i[2])) {                           \
        tk = L##k[2]; ti_ = L##i[2]; L##k[2] = L##k[3]; L##i[2] = L##i[3]; L##k[3] = tk; L##i[3] = ti_; \
        if (lexlt(L##k[2], L##i[2], L##k[1], L##i[1])) {                         \
          tk = L##k[1]; ti_ = L##i[1]; L##k[1] = L##k[2]; L##i[1] = L##i[2]; L##k[2] = tk; L##i[2] = ti_; \
          if (lexlt(L##k[1], L##i[1], L##k[0], L##i[0])) {                       \
            tk = L##k[0]; ti_ = L##i[0]; L##k[0] = L##k[1]; L##i[0] = L##i[1]; L##k[1] = tk; L##i[1] = ti_; \
          }                                                                      \
        }                                                                        \
      }                                                                          \
    }                                                                            \
  }

// ---------------- fused prep: fp32->bf16 + row sumsq/inv-norm ----------------
__global__ __launch_bounds__(192) void prep_kernel(const float* __restrict__ z1, const float* __restrict__ z2,
                                                   unsigned short* __restrict__ zb, float* __restrict__ sq,
                                                   float* __restrict__ inv) {
  int r = blockIdx.x;  // 0..16383
  const float* p = (r < 4 * TT) ? (z1 + (size_t)r * CC) : (z2 + (size_t)(r - 4 * TT) * CC);
  unsigned short* o = zb + (size_t)r * CC;
  float4 v = ((const float4*)p)[threadIdx.x];
  float s = v.x * v.x + v.y * v.y + v.z * v.z + v.w * v.w;
  ushort4 u;
  u.x = f2bf(v.x); u.y = f2bf(v.y); u.z = f2bf(v.z); u.w = f2bf(v.w);
  ((ushort4*)o)[threadIdx.x] = u;
#pragma unroll
  for (int off = 32; off > 0; off >>= 1) s += __shfl_down(s, off, 64);
  __shared__ float wred[3];
  int lane = threadIdx.x & 63, w = threadIdx.x >> 6;
  if (lane == 0) wred[w] = s;
  __syncthreads();
  if (threadIdx.x == 0) {
    float tot = wred[0] + wred[1] + wred[2];
    sq[r] = tot; inv[r] = rsqrtf(tot + 1e-12f);
  }
}

// ---------------- unified gram kernel: BK=64, XOR-swizzled LDS; bf16 gram via LDS-staged epilogue ----------------
// __launch_bounds__(256,4): cap VGPR at 128 (occupancy cliff) — R10/R11 hit 132 and halved occupancy
__global__ __launch_bounds__(256, 4) void gram_all(const unsigned short* __restrict__ zb, unsigned short* __restrict__ gram,
                                                   const float* __restrict__ invAll, PairTab tab,
                                                   float* __restrict__ prow_v, int* __restrict__ prow_i,
                                                   float* __restrict__ pcol_v, int* __restrict__ pcol_i) {
  __shared__ union {
    struct { unsigned short As[128 * 64]; unsigned short Bs[128 * 64]; } st;   // 32768 B (K-loop)
    unsigned short tile[128 * TP];                                             // 33792 B (self epilogue)
  } sm;
  __shared__ float sInvA[128], sInvB[128];
  __shared__ float rowv[2][128]; __shared__ int rowi[2][128];
  __shared__ float colv[2][128]; __shared__ int coli[2][128];

  const int bid = blockIdx.x;
  const bool isSelf = bid < N_SELF_BLK;
  int bm, bn, p = 0, s = 0;
  const unsigned short *A, *B;
  if (isSelf) {
    s = bid / 136;
    int t = bid % 136;
    int ti = 0;
    while (t >= 16 - ti) { t -= 16 - ti; ++ti; }
    int tj = ti + t;           // ti <= tj
    bm = ti * 128; bn = tj * 128;
    A = zb + (size_t)s * TT * CC;
    B = A;
  } else {
    int cb = bid - N_SELF_BLK;
    p = cb >> 8;
    int tile = cb & 255;
    bn = (tile & 15) * 128;
    bm = (tile >> 4) * 128;
    A = zb + (size_t)tab.sa[p] * TT * CC;
    B = zb + (size_t)tab.sb[p] * TT * CC;
    const float* invA = invAll + (size_t)tab.sa[p] * TT;
    const float* invB = invAll + (size_t)tab.sb[p] * TT;
    if (threadIdx.x < 128) sInvA[threadIdx.x] = invA[bm + threadIdx.x];
    else sInvB[threadIdx.x - 128] = invB[bn + threadIdx.x - 128];
  }
  const int lane = threadIdx.x & 63, waveId = threadIdx.x >> 6;
  const int wm = (waveId >> 1) * 64, wn = (waveId & 1) * 64;
  const int lrow = lane & 15, lquad = lane >> 4;

  float4v acc[4][4];
#pragma unroll
  for (int i = 0; i < 4; ++i)
#pragma unroll
    for (int j = 0; j < 4; ++j) acc[i][j] = (float4v){0.f, 0.f, 0.f, 0.f};

  for (int kk = 0; kk < CC; kk += 64) {
    // stage 128x64 per matrix; LDS slot l holds global chunk (l&7)^(row&7) -> swizzled (conflict-free)
#pragma unroll
    for (int c = 0; c < 4; ++c) {
      int l = c * 256 + threadIdx.x;        // 0..1023 chunks of 8 shorts
      int row = l >> 3, pc = l & 7;
      int sc = pc ^ (row & 7);
      gload_lds16(A + (size_t)(bm + row) * CC + kk + sc * 8, &sm.st.As[l * 8]);
      gload_lds16(B + (size_t)(bn + row) * CC + kk + sc * 8, &sm.st.Bs[l * 8]);
    }
    __syncthreads();
#pragma unroll
    for (int h = 0; h < 2; ++h) {
      short8 af[4], bfr[4];
#pragma unroll
      for (int i = 0; i < 4; ++i) {
        int ra = wm + i * 16 + lrow;
        int ca = (h * 4 + lquad) ^ (ra & 7);
        af[i] = *(const short8*)&sm.st.As[ra * 64 + ca * 8];
        int rb = wn + i * 16 + lrow;
        int cb2 = (h * 4 + lquad) ^ (rb & 7);
        bfr[i] = *(const short8*)&sm.st.Bs[rb * 64 + cb2 * 8];
      }
#pragma unroll
      for (int i = 0; i < 4; ++i)
#pragma unroll
        for (int j = 0; j < 4; ++j)
          acc[i][j] = __builtin_amdgcn_mfma_f32_16x16x32_bf16(af[i], bfr[j], acc[i][j], 0, 0, 0);
    }
    __syncthreads();
  }

  if (isSelf) {
    // ---- scatter acc -> LDS tile as bf16 ----
#pragma unroll
    for (int i = 0; i < 4; ++i)
#pragma unroll
      for (int j = 0; j < 4; ++j)
#pragma unroll
        for (int r = 0; r < 4; ++r) {
          int lr = wm + i * 16 + lquad * 4 + r;
          int lc = wn + j * 16 + lrow;
          sm.tile[lr * TP + lc] = f2bf(acc[i][j][r]);
        }
    __syncthreads();
    unsigned short* G = gram + (size_t)s * TT * TT;
    // ---- direct rows: coalesced 8B stores from LDS ----
    for (int it = 0; it < 16; ++it) {
      int task = it * 256 + threadIdx.x;
      int r = task >> 5;          // 0..127
      int c = task & 31;          // chunk of 4 ushorts
      short4v v = *(const short4v*)&sm.tile[r * TP + c * 4];
      *(short4v*)&G[(size_t)(bm + r) * TT + bn + c * 4] = v;
    }
    // ---- mirror rows (offdiag): transposed LDS reads, coalesced 8B stores ----
    if (bm != bn) {
      for (int it = 0; it < 16; ++it) {
        int task = it * 256 + threadIdx.x;
        int cc = task >> 5;       // mirror row = original col 0..127
        int q = task & 31;        // chunk of 4 original rows
        short4v v;
        v[0] = (short)sm.tile[(q * 4 + 0) * TP + cc];
        v[1] = (short)sm.tile[(q * 4 + 1) * TP + cc];
        v[2] = (short)sm.tile[(q * 4 + 2) * TP + cc];
        v[3] = (short)sm.tile[(q * 4 + 3) * TP + cc];
        *(short4v*)&G[(size_t)(bn + cc) * TT + bm + q * 4] = v;
      }
    }
    return;
  }

  // ---- cross: fused dual argmin partials (fp32 acc, unchanged) ----
  float rbv[4][4]; int rbi[4][4];
#pragma unroll
  for (int i = 0; i < 4; ++i)
#pragma unroll
    for (int r = 0; r < 4; ++r) { rbv[i][r] = INFINITY; rbi[i][r] = TT; }
#pragma unroll
  for (int i = 0; i < 4; ++i)
#pragma unroll
    for (int j = 0; j < 4; ++j) {
      int col = bn + wn + j * 16 + lrow;
      float ivb = sInvB[wn + j * 16 + lrow];
#pragma unroll
      for (int r = 0; r < 4; ++r) {
        float v = -acc[i][j][r] * ivb;
        if (v < rbv[i][r]) { rbv[i][r] = v; rbi[i][r] = col; }
      }
    }
#pragma unroll
  for (int m = 1; m <= 8; m <<= 1) {
#pragma unroll
    for (int i = 0; i < 4; ++i)
#pragma unroll
      for (int r = 0; r < 4; ++r) {
        float v2 = __shfl_xor(rbv[i][r], m, 64);
        int i2 = __shfl_xor(rbi[i][r], m, 64);
        if (v2 < rbv[i][r] || (v2 == rbv[i][r] && i2 < rbi[i][r])) { rbv[i][r] = v2; rbi[i][r] = i2; }
      }
  }
  if (lrow == 0) {
#pragma unroll
    for (int i = 0; i < 4; ++i)
#pragma unroll
      for (int r = 0; r < 4; ++r) {
        int lr = wm + i * 16 + lquad * 4 + r;
        rowv[wn >> 6][lr] = rbv[i][r]; rowi[wn >> 6][lr] = rbi[i][r];
      }
  }

  float cbv[4]; int cbi[4];
#pragma unroll
  for (int j = 0; j < 4; ++j) { cbv[j] = INFINITY; cbi[j] = TT; }
#pragma unroll
  for (int j = 0; j < 4; ++j)
#pragma unroll
    for (int i = 0; i < 4; ++i)
#pragma unroll
      for (int r = 0; r < 4; ++r) {
        int lr = wm + i * 16 + lquad * 4 + r;
        float v = -acc[i][j][r] * sInvA[lr];
        if (v < cbv[j]) { cbv[j] = v; cbi[j] = bm + lr; }
      }
#pragma unroll
  for (int m = 16; m <= 32; m <<= 1) {
#pragma unroll
    for (int j = 0; j < 4; ++j) {
      float v2 = __shfl_xor(cbv[j], m, 64);
      int i2 = __shfl_xor(cbi[j], m, 64);
      if (v2 < cbv[j] || (v2 == cbv[j] && i2 < cbi[j])) { cbv[j] = v2; cbi[j] = i2; }
    }
  }
  if (lquad == 0) {
#pragma unroll
    for (int j = 0; j < 4; ++j) {
      int lc = wn + j * 16 + lrow;
      colv[wm >> 6][lc] = cbv[j]; coli[wm >> 6][lc] = cbi[j];
    }
  }
  __syncthreads();

  int bj = bn >> 7, bi2 = bm >> 7;
  if (threadIdx.x < 128) {
    int t = threadIdx.x;
    float v0 = rowv[0][t], v1 = rowv[1][t];
    int i0 = rowi[0][t], i1 = rowi[1][t];
    bool take1 = (v1 < v0) || (v1 == v0 && i1 < i0);
    prow_v[((size_t)p * 16 + bj) * TT + bm + t] = take1 ? v1 : v0;
    prow_i[((size_t)p * 16 + bj) * TT + bm + t] = take1 ? i1 : i0;
  } else {
    int t = threadIdx.x - 128;
    float v0 = colv[0][t], v1 = colv[1][t];
    int i0 = coli[0][t], i1 = coli[1][t];
    bool take1 = (v1 < v0) || (v1 == v0 && i1 < i0);
    pcol_v[((size_t)p * 16 + bi2) * TT + bn + t] = take1 ? v1 : v0;
    pcol_i[((size_t)p * 16 + bi2) * TT + bn + t] = take1 ? i1 : i0;
  }
}

// ---------------- argmin stage 2 ----------------
__global__ __launch_bounds__(256) void argmin_reduce_batched(const float* __restrict__ prow_v, const int* __restrict__ prow_i,
                                                             const float* __restrict__ pcol_v, const int* __restrict__ pcol_i,
                                                             int* __restrict__ b_of_a, int* __restrict__ a_of_b) {
  int p = blockIdx.y;
  int t = blockIdx.x * 256 + threadIdx.x;
  int isRow = t < TT;
  int x = isRow ? t : t - TT;
  const float* pv = (isRow ? prow_v : pcol_v) + (size_t)p * 16 * TT;
  const int* pi = (isRow ? prow_i : pcol_i) + (size_t)p * 16 * TT;
  float best = INFINITY; int bidx = TT;
  for (int s = 0; s < 16; ++s) {
    float v = pv[(size_t)s * TT + x]; int id = pi[(size_t)s * TT + x];
    if (v < best || (v == best && id < bidx)) { best = v; bidx = id; }
  }
  if (isRow) b_of_a[(size_t)p * TT + x] = bidx;
  else       a_of_b[(size_t)p * TT + x] = bidx;
}

// ---------------- single-pass dual top-5: one wave per row (bf16 gram) ----------------
__global__ __launch_bounds__(256) void top5_batched(const unsigned short* __restrict__ gram, const float* __restrict__ sqAll,
                                                    const float* __restrict__ invAll, int* __restrict__ out0,
                                                    int* __restrict__ out1) {
  int s = blockIdx.y;
  int w = threadIdx.x >> 6, lane = threadIdx.x & 63;
  int i = blockIdx.x * 4 + w;
  const unsigned short* G = gram + (size_t)s * TT * TT + (size_t)i * TT;
  const float* sq = sqAll + (size_t)s * TT;
  const float* inv = invAll + (size_t)s * TT;

  float ak[5]; int ai[5];   // mode0 (sq-dist)
  float bk[5]; int bi[5];   // mode1 (cos-dist)
#pragma unroll
  for (int t = 0; t < 5; ++t) { ak[t] = INFINITY; ai[t] = TT; bk[t] = INFINITY; bi[t] = TT; }

#pragma unroll
  for (int step = 0; step < 8; ++step) {
    int j4 = (step * 64 + lane) * 4;
    ushort4 g4u = *(const ushort4*)&G[j4];
    float4 s4 = *(const float4*)&sq[j4];
    float4 v4 = *(const float4*)&inv[j4];
#pragma unroll
    for (int c = 0; c < 4; ++c) {
      int j = j4 + c;
      float g = bf2f((c == 0) ? g4u.x : (c == 1) ? g4u.y : (c == 2) ? g4u.z : g4u.w);
      float sv = (c == 0) ? s4.x : (c == 1) ? s4.y : (c == 2) ? s4.z : s4.w;
      float iv = (c == 0) ? v4.x : (c == 1) ? v4.y : (c == 2) ? v4.z : v4.w;
      float k0 = (j == i) ? INFINITY : sv - 2.f * g;
      float k1 = (j == i) ? INFINITY : -g * iv;
      INS5(k0, j, a)
      INS5(k1, j, b)
    }
  }
  // butterfly merge across 64 lanes
#pragma unroll
  for (int m = 1; m <= 32; m <<= 1) {
    float ok[5]; int oi[5];
#pragma unroll
    for (int t = 0; t < 5; ++t) { ok[t] = __shfl_xor(ak[t], m, 64); oi[t] = __shfl_xor(ai[t], m, 64); }
#pragma unroll
    for (int t = 0; t < 5; ++t) { INS5(ok[t], oi[t], a) }
#pragma unroll
    for (int t = 0; t < 5; ++t) { ok[t] = __shfl_xor(bk[t], m, 64); oi[t] = __shfl_xor(bi[t], m, 64); }
#pragma unroll
    for (int t = 0; t < 5; ++t) { INS5(ok[t], oi[t], b) }
  }
  if (lane < KK) {
    int v0 = (lane == 0) ? ai[0] : (lane == 1) ? ai[1] : (lane == 2) ? ai[2] : (lane == 3) ? ai[3] : ai[4];
    int v1 = (lane == 0) ? bi[0] : (lane == 1) ? bi[1] : (lane == 2) ? bi[2] : (lane == 3) ? bi[3] : bi[4];
    out0[((size_t)s * TT + i) * KK + lane] = v0;
    out1[((size_t)s * TT + i) * KK + lane] = v1;
  }
}

// ---------------- mutual matching, batched ----------------
__global__ __launch_bounds__(256) void mutual_batched(const int* __restrict__ b_of_a_all,
                                                      const int* __restrict__ a_of_b_all,
                                                      int* __restrict__ idxB_all, int* __restrict__ matchedB_all,
                                                      int* __restrict__ unmatched_all, int* __restrict__ scalars_all) {
  int p = blockIdx.x;
  const int* b_of_a = b_of_a_all + (size_t)p * TT;
  const int* a_of_b = a_of_b_all + (size_t)p * TT;
  int* idxB_of_A = idxB_all + (size_t)p * TT;
  int* matchedB = matchedB_all + (size_t)p * TT;
  int* unmatched = unmatched_all + (size_t)p * TT;
  __shared__ int cnt_sh;
  for (int j = threadIdx.x; j < TT; j += 256) matchedB[j] = 0;
  __syncthreads();
  for (int i = threadIdx.x; i < TT; i += 256) {
    int b = b_of_a[i];
    bool mut = (a_of_b[b] == i);
    idxB_of_A[i] = mut ? b : -1;
    if (mut) matchedB[b] = 1;
  }
  __syncthreads();
  if (threadIdx.x == 0) cnt_sh = 0;
  __syncthreads();
  for (int j = threadIdx.x; j < TT; j += 256) {
    if (!matchedB[j]) { int q = atomicAdd(&cnt_sh, 1); unmatched[q] = j; }
  }
  __syncthreads();
  if (threadIdx.x == 0) {
    int c = cnt_sh;
    if (c == 0) { unmatched[0] = 0; c = 1; }
    scalars_all[p * 16] = c;
  }
}

// ---------------- crossbrain hinge: 64 rows/block, 1 atomic/block ----------------
__global__ __launch_bounds__(256) void cb_hinge_block(const unsigned short* __restrict__ gram, const float* __restrict__ invAll,
                                                      const int* __restrict__ neigh1, float* __restrict__ cb_acc) {
  int c = blockIdx.y;
  int i0 = blockIdx.x * 64;
  int sa = c, sb = (c < 4) ? (c + 4) : (c - 4);
  const unsigned short* Gs = gram + (size_t)sb * TT * TT;
  const float* invB = invAll + (size_t)sb * TT;
  const int* neighA = neigh1 + (size_t)sa * TT * KK;
  unsigned int seed = 0x13579BDFu + 0x9E3779B9u * (unsigned)c;
  int tid = threadIdx.x;

  __shared__ int targ[64][10];
  __shared__ float sval[64][10];
  for (int t = tid; t < 64 * KK; t += 256) targ[t / KK][t % KK] = neighA[(size_t)i0 * KK + t];
  __syncthreads();
  if (tid < 64) {
    int i = i0 + tid;
    int pos[KK];
#pragma unroll
    for (int k = 0; k < KK; ++k) pos[k] = targ[tid][k];
    unsigned int ctr = 0;
    for (int k = 0; k < KK; ++k) {
      int cand;
      while (true) {
        unsigned int h = mix_hash(seed ^ (unsigned)i, ctr++);
        cand = (int)(h & (TT - 1));
        bool bad = (cand == i);
        for (int t = 0; t < KK; ++t) bad = bad || (cand == pos[t]);
        for (int t = 0; t < k; ++t) bad = bad || (cand == targ[tid][KK + t]);
        if (!bad) break;
      }
      targ[tid][KK + k] = cand;
    }
  }
  __syncthreads();
  for (int t = tid; t < 640; t += 256) {
    int il = t / 10, k = t % 10;
    int tt = targ[il][k];
    sval[il][k] = bf2f(Gs[(size_t)(i0 + il) * TT + tt]) * invB[tt];
  }
  __syncthreads();
  if (tid < 64) {
    int i = i0 + tid;
    float ii = invB[i];
    const float lo = -1.f + 1e-8f, hi = 1.f - 1e-8f;
    float hsum = 0.f;
#pragma unroll
    for (int k = 0; k < KK; ++k) {
      float sp = fminf(fmaxf(sval[tid][k] * ii, lo), hi);
      float sn = fminf(fmaxf(sval[tid][KK + k] * ii, lo), hi);
      float h = sn - sp + 0.05f;
      hsum += (h > 0.f) ? h : 0.f;
    }
#pragma unroll
    for (int off = 32; off > 0; off >>= 1) hsum += __shfl_down(hsum, off, 64);
    if (tid == 0) atomicAdd(&cb_acc[c], hsum);
  }
}

// ---------------- NRC hinge: 64 rows/block, 2 atomics/block ----------------
__global__ __launch_bounds__(256) void nrc_hinge_block(const unsigned short* __restrict__ gram, const float* __restrict__ invAll,
                                                       const int* __restrict__ neighC, const int* __restrict__ idxB_all,
                                                       const int* __restrict__ unmatched_all,
                                                       const int* __restrict__ scalars_all,
                                                       PairTab tab, float* __restrict__ nrc_acc) {
  int p = blockIdx.y;
  int i0 = blockIdx.x * 64;
  int sa = tab.sa[p], sb = tab.sb[p];
  const unsigned short* Gs = gram + (size_t)sb * TT * TT;
  const float* invB = invAll + (size_t)sb * TT;
  const int* neighA = neighC + (size_t)sa * TT * KK;
  const int* idxB_of_A = idxB_all + (size_t)p * TT;
  const int* unmatched = unmatched_all + (size_t)p * TT;
  unsigned int seed = 0xC0FFEE11u + 0x9E3779B9u * (unsigned)p;
  float* acc = nrc_acc + p * 2;
  int tid = threadIdx.x;

  __shared__ int targ[64][10];
  __shared__ float sval[64][10];
  __shared__ unsigned int tmask[64];
  __shared__ int su[64];
  if (tid < 64) { tmask[tid] = 0; su[tid] = idxB_of_A[i0 + tid]; }
  __syncthreads();
  unsigned int neg_count = (unsigned int)scalars_all[p * 16];
  for (int t = tid; t < 64 * KK; t += 256) {
    int il = t / KK, k = t % KK;
    int nb = neighA[(size_t)i0 * KK + t];
    int pb = idxB_of_A[nb];
    targ[il][k] = (pb >= 0) ? pb : 0;
    if (pb >= 0) atomicOr(&tmask[il], 1u << k);
  }
  for (int t = tid; t < 64 * KK; t += 256) {
    int il = t / KK, k = t % KK;
    int i = i0 + il;
    unsigned int r = mix_hash(seed ^ 0xA5A5u, (unsigned)(i * KK + k)) & (TT - 1);
    targ[il][KK + k] = unmatched[r % neg_count];
  }
  __syncthreads();
  for (int t = tid; t < 640; t += 256) {
    int il = t / 10, k = t % 10;
    int u = su[il] >= 0 ? su[il] : 0;
    int tt = targ[il][k];
    sval[il][k] = bf2f(Gs[(size_t)u * TT + tt]) * invB[tt];
  }
  __syncthreads();
  if (tid < 64) {
    int idx = su[tid];
    int u = idx >= 0 ? idx : 0;
    float iu = invB[u];
    unsigned int tm = tmask[tid];
    float hsum = 0.f; int pcnt = 0;
#pragma unroll
    for (int k = 0; k < KK; ++k) {
      if (tm & (1u << k)) {
        float dpos = 1.f - sval[tid][k] * iu;
        float dneg = 1.f - sval[tid][KK + k] * iu;
        float h = dpos - dneg + 0.4f;
        hsum += (h > 0.f) ? h : 0.f;
        pcnt++;
      }
    }
    float hs = 0.f, vc = 0.f;
    if (idx >= 0 && pcnt > 0) { hs = hsum / (float)pcnt; vc = 1.0f; }
#pragma unroll
    for (int off = 32; off > 0; off >>= 1) {
      hs += __shfl_down(hs, off, 64);
      vc += __shfl_down(vc, off, 64);
    }
    if (tid == 0) {
      atomicAdd(&acc[0], hs);
      atomicAdd(&acc[1], vc);
    }
  }
}

// ---------------- final combine ----------------
__global__ void final_kernel(const float* __restrict__ cb_acc, const float* __restrict__ nrc_acc,
                             float* __restrict__ out) {
  float loss2 = 0.f;
  for (int c = 0; c < 8; ++c) loss2 += cb_acc[c] * (1.0f / 10240.0f);
  loss2 *= 0.25f;
  float loss3 = 0.f;
  for (int d = 0; d < 2; ++d) {
    float s = 0.f;
    for (int t = 0; t < 6; ++t) {
      float cnt = nrc_acc[(d * 6 + t) * 2 + 1];
      float sum = nrc_acc[(d * 6 + t) * 2 + 0];
      s += (cnt > 0.f) ? (sum / cnt) : 0.f;
    }
    loss3 += s * (1.f / 6.f);
  }
  out[0] = 10.f * loss2 + 10.f * loss3;
}

// ---------------- host-side numpy RandomState(seed).permutation(12)[:6] ----------------
namespace {
struct MT19937 {
  uint32_t mt[624]; int mti;
  void seed(uint32_t s) {
    mt[0] = s;
    for (int i = 1; i < 624; ++i) mt[i] = 1812433253u * (mt[i - 1] ^ (mt[i - 1] >> 30)) + (uint32_t)i;
    mti = 624;
  }
  uint32_t next() {
    if (mti >= 624) {
      for (int i = 0; i < 624; ++i) {
        uint32_t y = (mt[i] & 0x80000000u) | (mt[(i + 1) % 624] & 0x7fffffffu);
        uint32_t v = y >> 1;
        if (y & 1u) v ^= 0x9908b0dfu;
        mt[i] = mt[(i + 397) % 624] ^ v;
      }
      mti = 0;
    }
    uint32_t y = mt[mti++];
    y ^= y >> 11; y ^= (y << 7) & 0x9d2c5680u; y ^= (y << 15) & 0xefc60000u; y ^= y >> 18;
    return y;
  }
  uint32_t interval(uint32_t mx) {
    uint32_t mask = mx;
    mask |= mask >> 1; mask |= mask >> 2; mask |= mask >> 4; mask |= mask >> 8; mask |= mask >> 16;
    while (true) { uint32_t v = next() & mask; if (v <= mx) return v; }
  }
};
inline void np_perm12_first6(uint32_t seed, int* sel6) {
  int a[12]; for (int i = 0; i < 12; ++i) a[i] = i;
  MT19937 r; r.seed(seed);
  for (int i = 11; i >= 1; --i) { uint32_t j = r.interval((uint32_t)i); int t = a[i]; a[i] = a[j]; a[j] = t; }
  for (int i = 0; i < 6; ++i) sel6[i] = a[i];
}
}  // namespace

extern "C" void kernel_launch(void* const* d_in, const int* in_sizes, int n_in,
                              void* d_out, int out_size, void* d_ws, size_t ws_size,
                              hipStream_t stream) {
  const float* z1 = (const float*)d_in[0];
  const float* z2 = (const float*)d_in[1];
  float* out = (float*)d_out;

  char* base = (char*)d_ws;
  size_t off = 0;
  auto alloc = [&](size_t bytes) -> void* {
    void* p = base + off;
    off = (off + bytes + 255) & ~(size_t)255;
    return p;
  };
  unsigned short* gram   = (unsigned short*)alloc((size_t)8 * TT * TT * 2);  // 67 MB bf16 self grams
  unsigned short* zb     = (unsigned short*)alloc((size_t)8 * TT * CC * 2);
  float* sq              = (float*)alloc((size_t)8 * TT * 4);
  float* inv             = (float*)alloc((size_t)8 * TT * 4);
  int*   neigh1          = (int*)alloc((size_t)8 * TT * KK * 4);
  int*   neighC          = (int*)alloc((size_t)8 * TT * KK * 4);
  float* prow_v          = (float*)alloc((size_t)12 * 16 * TT * 4);
  int*   prow_i          = (int*)alloc((size_t)12 * 16 * TT * 4);
  float* pcol_v          = (float*)alloc((size_t)12 * 16 * TT * 4);
  int*   pcol_i          = (int*)alloc((size_t)12 * 16 * TT * 4);
  int*   b_of_a          = (int*)alloc((size_t)12 * TT * 4);
  int*   a_of_b          = (int*)alloc((size_t)12 * TT * 4);
  int*   idxB            = (int*)alloc((size_t)12 * TT * 4);
  int*   matchedB        = (int*)alloc((size_t)12 * TT * 4);
  int*   unmatched       = (int*)alloc((size_t)12 * TT * 4);
  int*   scalars         = (int*)alloc(12 * 16 * 4);
  float* accs            = (float*)alloc(64 * 4);
  float* cb_acc          = accs;
  float* nrc_acc         = accs + 8;

  hipMemsetAsync(accs, 0, 64 * 4, stream);

  // NRC pair selection (numpy RandomState(seed).permutation(12)[:6])
  int sel0[6], sel1[6];
  np_perm12_first6(0u, sel0);
  np_perm12_first6(1u, sel1);
  static const int PP[12] = {0, 0, 0, 1, 1, 1, 2, 2, 2, 3, 3, 3};
  static const int QQ[12] = {1, 2, 3, 0, 2, 3, 0, 1, 3, 0, 1, 2};
  PairTab tab;
  for (int d = 0; d < 2; ++d) {
    const int* sel = (d == 0) ? sel0 : sel1;
    for (int t = 0; t < 6; ++t) {
      int pi_ = PP[sel[t]], qi = QQ[sel[t]];
      int p = d * 6 + t;
      tab.sa[p] = (d == 0) ? pi_ : 4 + pi_;
      tab.sb[p] = (d == 0) ? 4 + qi : qi;
    }
  }

  // fused prep (bf16 convert + norms)
  prep_kernel<<<8 * TT, 192, 0, stream>>>(z1, z2, zb, sq, inv);

  // unified gram: self upper-triangle (bf16 store via LDS staging, mirror) + cross with fused argmin
  gram_all<<<N_SELF_BLK + N_CROSS_BLK, 256, 0, stream>>>(zb, gram, inv, tab, prow_v, prow_i, pcol_v, pcol_i);

  // self-dependent phase
  top5_batched<<<dim3(TT / 4, 8), 256, 0, stream>>>(gram, sq, inv, neigh1, neighC);
  cb_hinge_block<<<dim3(TT / 64, 8), 256, 0, stream>>>(gram, inv, neigh1, cb_acc);

  // cross-dependent phase
  argmin_reduce_batched<<<dim3(2 * TT / 256, 12), 256, 0, stream>>>(prow_v, prow_i, pcol_v, pcol_i, b_of_a, a_of_b);
  mutual_batched<<<12, 256, 0, stream>>>(b_of_a, a_of_b, idxB, matchedB, unmatched, scalars);
  nrc_hinge_block<<<dim3(TT / 64, 12), 256, 0, stream>>>(gram, inv, neighC, idxB, unmatched, scalars, tab, nrc_acc);

  final_kernel<<<1, 1, 0, stream>>>(cb_acc, nrc_acc, out);
}